// Round 5
// baseline (225.681 us; speedup 1.0000x reference)
//
#include <hip/hip_runtime.h>
#include <hip/hip_bf16.h>

#define N_NODES 10000
#define N_EDGES 640000
#define CH 128
#define NB 64                // histogram/scatter blocks
#define EPB (N_EDGES / NB)   // 10000 edges per block
#define NCHUNK 40            // ceil(N_NODES/256) scan chunks
#define NPAD 10240           // NCHUNK*256

// ---------------------------------------------------------------------------
// K1: FUSED. Blocks [0,NB): per-block LDS DUAL histogram (count + weighted
// degree, 80 KB) + chunk count-partials. Blocks [NB, NB+157): gemm1 = x@W1^T.
// Block NB+157: conv/fc weight fold.
__global__ __launch_bounds__(256) void fused_hist_gemm(const int* __restrict__ ei,
        const float* __restrict__ ew,
        const float* __restrict__ x, const float* __restrict__ W1,
        int* __restrict__ hist, float* __restrict__ dhist, int* __restrict__ pcs,
        float* __restrict__ out,
        const float* __restrict__ conv_w, const float* __restrict__ conv_b,
        const float* __restrict__ fc_w, const float* __restrict__ fc_b,
        float* __restrict__ vbuf, float* __restrict__ c0) {
    __shared__ __align__(16) char smem[NPAD * 8];    // 80 KB union
    int t = threadIdx.x;
    int bid = blockIdx.x;
    if (bid < NB) {
        // ---- dual histogram path ----
        int* h = (int*)smem;                         // 40 KB counts
        float* hf = (float*)(smem + NPAD * 4);       // 40 KB weighted degree
        for (int i = t; i < 2 * NPAD; i += 256) ((int*)smem)[i] = 0;
        __syncthreads();
        int e0 = bid * EPB;
        for (int i = t; i < EPB; i += 256) {
            int e = e0 + i;
            int c = ei[N_EDGES + e];
            atomicAdd(&h[c], 1);                     // LDS atomics
            atomicAdd(&hf[c], ew[e]);
        }
        __syncthreads();
        for (int i = t; i < N_NODES; i += 256) {
            hist[bid * N_NODES + i] = h[i];
            dhist[bid * N_NODES + i] = hf[i];
        }
        // chunk count partials: wave w handles chunks w, w+4, ...
        int lane = t & 63, wave = t >> 6;
        for (int cch = wave; cch < NCHUNK; cch += 4) {
            int s = h[cch * 256 + lane] + h[cch * 256 + lane + 64]
                  + h[cch * 256 + lane + 128] + h[cch * 256 + lane + 192];
            #pragma unroll
            for (int off = 32; off > 0; off >>= 1) s += __shfl_down(s, off, 64);
            if (lane == 0) pcs[cch * NB + bid] = s;  // chunk-major layout
        }
        return;
    }
    if (bid == NB + (N_NODES + 63) / 64) {
        // ---- conv/fc weight folding ----
        for (int i = t; i <= 384; i += 256) {
            if (i < 384) {
                float s = 0.0f;
                for (int o = 0; o < CH; ++o) s += fc_w[o] * conv_w[o * 384 + i];
                vbuf[i] = s;
            } else {
                float s = fc_b[0];
                for (int o = 0; o < CH; ++o) s += fc_w[o] * conv_b[o];
                *c0 = s;
            }
        }
        return;
    }
    // ---- gemm path: out[m][o] = sum_k x[m][k] * W1[o][k] ----
    float (*As)[68]  = (float(*)[68])smem;
    float (*Ws)[132] = (float(*)[132])(smem + 32 * 68 * sizeof(float));
    int tx = t & 31;
    int ty = t >> 5;
    int row0 = (bid - NB) * 64;
    float acc[8][4] = {};
    for (int k0 = 0; k0 < 128; k0 += 32) {
        #pragma unroll
        for (int i = 0; i < 8; ++i) {
            int idx = t + i * 256;
            int r = idx >> 5, k = idx & 31;
            int gr = row0 + r;
            As[k][r] = (gr < N_NODES) ? x[gr * CH + k0 + k] : 0.0f;
        }
        #pragma unroll
        for (int i = 0; i < 16; ++i) {
            int idx = t + i * 256;
            int o = idx >> 5, k = idx & 31;
            Ws[k][o] = W1[o * CH + k0 + k];
        }
        __syncthreads();
        #pragma unroll
        for (int kk = 0; kk < 32; ++kk) {
            float a[8], w[4];
            #pragma unroll
            for (int j = 0; j < 8; ++j) a[j] = As[kk][ty * 8 + j];
            #pragma unroll
            for (int c = 0; c < 4; ++c) w[c] = Ws[kk][tx * 4 + c];
            #pragma unroll
            for (int j = 0; j < 8; ++j)
                #pragma unroll
                for (int c = 0; c < 4; ++c)
                    acc[j][c] += a[j] * w[c];
        }
        __syncthreads();
    }
    #pragma unroll
    for (int j = 0; j < 8; ++j) {
        int gr = row0 + ty * 8 + j;
        if (gr < N_NODES) {
            float4 v = make_float4(acc[j][0], acc[j][1], acc[j][2], acc[j][3]);
            *reinterpret_cast<float4*>(&out[gr * CH + tx * 4]) = v;
        }
    }
}

// ---------------------------------------------------------------------------
// K2: per-node totals + dinv + global exclusive prefix + cursor conversion.
__global__ __launch_bounds__(256) void bofs_kernel(int* __restrict__ hist,
        const float* __restrict__ dhist, const int* __restrict__ pcs,
        int* __restrict__ tot, int* __restrict__ offs, float* __restrict__ dinv) {
    __shared__ int wred[4];
    __shared__ int wsum[4];
    __shared__ int base_sh;
    int blk = blockIdx.x, t = threadIdx.x;
    int lane = t & 63, wave = t >> 6;
    // --- base = edges into nodes of earlier chunks ---
    int bsum = 0;
    for (int i = t; i < blk * NB; i += 256) bsum += pcs[i];
    #pragma unroll
    for (int off = 32; off > 0; off >>= 1) bsum += __shfl_down(bsum, off, 64);
    if (lane == 0) wred[wave] = bsum;
    __syncthreads();
    if (t == 0) base_sh = wred[0] + wred[1] + wred[2] + wred[3];
    // --- per-node totals (count + weighted degree) over 64 hist rows ---
    int n = blk * 256 + t;
    int v = 0;
    if (n < N_NODES) {
        float dsum = 0.0f;
        #pragma unroll 8
        for (int b = 0; b < NB; ++b) {
            v += hist[b * N_NODES + n];
            dsum += dhist[b * N_NODES + n];
        }
        tot[n] = v;
        dinv[n] = rsqrtf(dsum + 1.0f);            // +1 = self-loop weight
    }
    // --- 256-wide scan (wave scan + wave offsets) ---
    int s = v;
    #pragma unroll
    for (int off = 1; off < 64; off <<= 1) {
        int u = __shfl_up(s, off, 64);
        if (lane >= off) s += u;
    }
    if (lane == 63) wsum[wave] = s;
    __syncthreads();
    int wbase = 0;
    for (int i = 0; i < wave; ++i) wbase += wsum[i];
    if (n < N_NODES) {
        int run = base_sh + wbase + s - v;        // global exclusive prefix
        offs[n] = run;
        for (int b = 0; b < NB; ++b) {
            int h = hist[b * N_NODES + n];
            hist[b * N_NODES + n] = run;          // column -> start cursor
            run += h;
        }
    }
}

// ---------------------------------------------------------------------------
// K3: scatter edges into CSR order via LDS cursors; records carry the fully
// NORMALIZED value dinv[r]*w*dinv[c] (dinv staged in LDS).
__global__ __launch_bounds__(256) void scatter_kernel(const int* __restrict__ ei,
        const float* __restrict__ ew, const float* __restrict__ dinv,
        const int* __restrict__ bofs, int2* __restrict__ erec) {
    __shared__ int cur[N_NODES];                 // 40 KB
    __shared__ float di[N_NODES];                // 40 KB
    int b = blockIdx.x, t = threadIdx.x;
    for (int i = t; i < N_NODES; i += 256) {
        cur[i] = bofs[b * N_NODES + i];
        di[i] = dinv[i];
    }
    __syncthreads();
    int e0 = b * EPB;
    for (int i = t; i < EPB; i += 256) {
        int e = e0 + i;
        int r = ei[e];
        int c = ei[N_EDGES + e];
        float v = di[r] * ew[e] * di[c];
        int p = atomicAdd(&cur[c], 1);           // LDS atomic
        erec[p] = make_int2(r, __float_as_int(v));
    }
}

// ---------------------------------------------------------------------------
// K4: FUSED agg1 + gemm2 — ARM A: 16-deep gather batches (2x MLP).
__global__ __launch_bounds__(256) void agg_gemm_kernel(const float4* __restrict__ xw4,
        const int2* __restrict__ erec, const int* __restrict__ offs,
        const int* __restrict__ cnt, const float* __restrict__ dinv,
        const float4* __restrict__ bias4, const float* __restrict__ W2,
        float* __restrict__ out) {
    __shared__ float hs[8][128];                 // 4 KB relu'd h1 rows
    int l = threadIdx.x & 31;                    // channel quad
    int g = threadIdx.x >> 5;                    // node group 0..7
    int n = blockIdx.x * 8 + g;
    float d = dinv[n];
    float dd = d * d;
    float4 self = xw4[n * 32 + l];
    float4 acc = make_float4(dd * self.x, dd * self.y, dd * self.z, dd * self.w);
    int start = offs[n];
    int num = cnt[n];
    int i = 0;
    for (; i + 16 <= num; i += 16) {
        int2 r[16];
        #pragma unroll
        for (int j = 0; j < 16; ++j) r[j] = erec[start + i + j];
        float4 f[16];
        #pragma unroll
        for (int j = 0; j < 16; ++j) f[j] = xw4[r[j].x * 32 + l];
        #pragma unroll
        for (int j = 0; j < 16; ++j) {
            float v = __int_as_float(r[j].y);
            acc.x += v * f[j].x; acc.y += v * f[j].y;
            acc.z += v * f[j].z; acc.w += v * f[j].w;
        }
    }
    for (; i + 8 <= num; i += 8) {
        int2 r[8];
        #pragma unroll
        for (int j = 0; j < 8; ++j) r[j] = erec[start + i + j];
        float4 f[8];
        #pragma unroll
        for (int j = 0; j < 8; ++j) f[j] = xw4[r[j].x * 32 + l];
        #pragma unroll
        for (int j = 0; j < 8; ++j) {
            float v = __int_as_float(r[j].y);
            acc.x += v * f[j].x; acc.y += v * f[j].y;
            acc.z += v * f[j].z; acc.w += v * f[j].w;
        }
    }
    for (; i < num; ++i) {
        int2 r = erec[start + i];
        float4 f = xw4[r.x * 32 + l];
        float v = __int_as_float(r.y);
        acc.x += v * f.x; acc.y += v * f.y; acc.z += v * f.z; acc.w += v * f.w;
    }
    float4 bb = bias4[l];
    acc.x = fmaxf(acc.x + bb.x, 0.0f);
    acc.y = fmaxf(acc.y + bb.y, 0.0f);
    acc.z = fmaxf(acc.z + bb.z, 0.0f);
    acc.w = fmaxf(acc.w + bb.w, 0.0f);
    *reinterpret_cast<float4*>(&hs[g][4 * l]) = acc;
    __syncthreads();
    // ---- mini-GEMM: thread = (output channel o, row-group rg of 4 rows) ----
    int o = threadIdx.x & 127;
    int rg = threadIdx.x >> 7;                   // 0: rows 0-3, 1: rows 4-7
    const float4* w4p = reinterpret_cast<const float4*>(&W2[o * CH]);
    const float4* h0p = reinterpret_cast<const float4*>(&hs[rg * 4 + 0][0]);
    const float4* h1p = reinterpret_cast<const float4*>(&hs[rg * 4 + 1][0]);
    const float4* h2p = reinterpret_cast<const float4*>(&hs[rg * 4 + 2][0]);
    const float4* h3p = reinterpret_cast<const float4*>(&hs[rg * 4 + 3][0]);
    float a0 = 0.0f, a1 = 0.0f, a2 = 0.0f, a3 = 0.0f;
    #pragma unroll 8
    for (int k4 = 0; k4 < 32; ++k4) {
        float4 w = w4p[k4];                      // L2-hot W2 row
        float4 h0 = h0p[k4], h1 = h1p[k4], h2 = h2p[k4], h3 = h3p[k4];
        a0 += w.x * h0.x + w.y * h0.y + w.z * h0.z + w.w * h0.w;
        a1 += w.x * h1.x + w.y * h1.y + w.z * h1.z + w.w * h1.w;
        a2 += w.x * h2.x + w.y * h2.y + w.z * h2.z + w.w * h2.w;
        a3 += w.x * h3.x + w.y * h3.y + w.z * h3.z + w.w * h3.w;
    }
    int nb = blockIdx.x * 8 + rg * 4;
    out[(nb + 0) * CH + o] = a0;
    out[(nb + 1) * CH + o] = a1;
    out[(nb + 2) * CH + o] = a2;
    out[(nb + 3) * CH + o] = a3;
}

// ---------------------------------------------------------------------------
// K5: aggregation layer 2 — ARM B: channel-split half-pass. Each dispatch
// touches only 64 of 128 channels -> hot gather table 2.56 MB, FITS per-XCD
// L2 (4 MB). 32 lanes/node, float2/lane, 16-deep batches.
__global__ __launch_bounds__(256) void agg_half_kernel(const float* __restrict__ xw,
        const int2* __restrict__ erec, const int* __restrict__ offs,
        const int* __restrict__ cnt, const float* __restrict__ dinv,
        const float* __restrict__ bias, float* __restrict__ out, int half) {
    int l = threadIdx.x & 31;                    // channel pair within half
    int g = threadIdx.x >> 5;                    // node group 0..7
    int n = blockIdx.x * 8 + g;
    int cidx = half * 32 + l;                    // float2 index within row
    const float2* xw2 = (const float2*)xw;
    float d = dinv[n];
    float dd = d * d;
    float2 self = xw2[n * 64 + cidx];
    float2 acc = make_float2(dd * self.x, dd * self.y);
    int start = offs[n];
    int num = cnt[n];
    int i = 0;
    for (; i + 16 <= num; i += 16) {
        int2 r[16];
        #pragma unroll
        for (int j = 0; j < 16; ++j) r[j] = erec[start + i + j];
        float2 f[16];
        #pragma unroll
        for (int j = 0; j < 16; ++j) f[j] = xw2[r[j].x * 64 + cidx];
        #pragma unroll
        for (int j = 0; j < 16; ++j) {
            float v = __int_as_float(r[j].y);
            acc.x += v * f[j].x; acc.y += v * f[j].y;
        }
    }
    for (; i < num; ++i) {
        int2 r = erec[start + i];
        float2 f = xw2[r.x * 64 + cidx];
        float v = __int_as_float(r.y);
        acc.x += v * f.x; acc.y += v * f.y;
    }
    float2 bb = ((const float2*)bias)[cidx];
    acc.x = fmaxf(acc.x + bb.x, 0.0f);
    acc.y = fmaxf(acc.y + bb.y, 0.0f);
    ((float2*)out)[n * 64 + cidx] = acc;
}

// ---------------------------------------------------------------------------
// K6: fused temporal conv + fc: one wave per node, lane handles ch l and l+64.
__global__ __launch_bounds__(256) void convfc_kernel(const float* __restrict__ h,
        const float* __restrict__ v, const float* __restrict__ c0,
        float* __restrict__ out, int N) {
    int n = blockIdx.x * 4 + (threadIdx.x >> 6);
    int l = threadIdx.x & 63;
    if (n >= N) return;
    const float* hn = h + n * CH;
    float v0a = v[l * 3 + 0],        v1a = v[l * 3 + 1],        v2a = v[l * 3 + 2];
    float v0b = v[(l + 64) * 3 + 0], v1b = v[(l + 64) * 3 + 1], v2b = v[(l + 64) * 3 + 2];
    float p = hn[l] * v1a + hn[l + 64] * v1b;
    if (n > 0)     p += hn[l - CH] * v0a + hn[l + 64 - CH] * v0b;
    if (n < N - 1) p += hn[l + CH] * v2a + hn[l + 64 + CH] * v2b;
    #pragma unroll
    for (int off = 32; off > 0; off >>= 1) p += __shfl_down(p, off, 64);
    if (l == 0) out[n] = p + *c0;
}

// ---------------------------------------------------------------------------
extern "C" void kernel_launch(void* const* d_in, const int* in_sizes, int n_in,
                              void* d_out, int out_size, void* d_ws, size_t ws_size,
                              hipStream_t stream) {
    const float* x       = (const float*)d_in[0];
    const int*   ei      = (const int*)d_in[1];
    const float* ew      = (const float*)d_in[2];
    const float* W1      = (const float*)d_in[3];
    const float* b1      = (const float*)d_in[4];
    const float* W2      = (const float*)d_in[5];
    const float* b2      = (const float*)d_in[6];
    const float* conv_w  = (const float*)d_in[7];
    const float* conv_b  = (const float*)d_in[8];
    const float* fc_w    = (const float*)d_in[9];
    const float* fc_b    = (const float*)d_in[10];
    float* out = (float*)d_out;

    float* bufA   = (float*)d_ws;                   // 1,280,000 f (xw1, later h2)
    float* bufB   = bufA + N_NODES * CH;            // 1,280,000 f (xw2)
    int2*  erec   = (int2*)(bufB + N_NODES * CH);   // 640,000 x 8B
    int*   hist   = (int*)(erec + N_EDGES);         // NB*10,000 i
    float* dhist  = (float*)(hist + NB * N_NODES);  // NB*10,000 f
    int*   pcs    = (int*)(dhist + NB * N_NODES);   // NCHUNK*NB i
    int*   tot    = pcs + NCHUNK * NB;              // 10,000 i
    int*   offs   = tot + N_NODES;                  // 10,000 i
    float* dinv   = (float*)(offs + N_NODES);       // 10,000 f
    float* vbuf   = dinv + N_NODES;                 // 384 f
    float* c0     = vbuf + 384;                     // 1 f

    const int gemm_grid = (N_NODES + 63) / 64;      // 157

    // K1: dual-hist (64) + gemm1 (157) + weight-fold (1), all data-independent
    fused_hist_gemm<<<NB + gemm_grid + 1, 256, 0, stream>>>(ei, ew, x, W1,
            hist, dhist, pcs, bufA, conv_w, conv_b, fc_w, fc_b, vbuf, c0);
    // K2: totals + dinv + prefix + cursor conversion
    bofs_kernel<<<NCHUNK, 256, 0, stream>>>(hist, dhist, pcs, tot, offs, dinv);
    // K3: normalized CSR scatter
    scatter_kernel<<<NB, 256, 0, stream>>>(ei, ew, dinv, hist, erec);
    // K4 (ARM A): agg1 + gemm2 fused, 16-deep MLP: bufA -> bufB
    agg_gemm_kernel<<<N_NODES / 8, 256, 0, stream>>>((const float4*)bufA, erec, offs,
            tot, dinv, (const float4*)b1, W2, bufB);
    // K5 (ARM B): agg layer 2 as two sequential channel-half passes: bufB -> bufA
    agg_half_kernel<<<N_NODES / 8, 256, 0, stream>>>(bufB, erec, offs, tot,
                                                     dinv, b2, bufA, 0);
    agg_half_kernel<<<N_NODES / 8, 256, 0, stream>>>(bufB, erec, offs, tot,
                                                     dinv, b2, bufA, 1);
    // K6: fused temporal conv + fc
    convfc_kernel<<<(N_NODES + 3) / 4, 256, 0, stream>>>(bufA, vbuf, c0, out, N_NODES);
}

// Round 6
// 212.647 us; speedup vs baseline: 1.0613x; 1.0613x over previous
//
#include <hip/hip_runtime.h>
#include <hip/hip_bf16.h>

#define N_NODES 10000
#define N_EDGES 640000
#define CH 128
#define NB 64                // histogram/scatter blocks
#define EPB (N_EDGES / NB)   // 10000 edges per block
#define NCHUNK 40            // ceil(N_NODES/256) scan chunks
#define NPAD 10240           // NCHUNK*256

// ---------------------------------------------------------------------------
// K1: FUSED. Blocks [0,NB): per-block LDS DUAL histogram (count + weighted
// degree, 80 KB) + chunk count-partials. Blocks [NB, NB+157): gemm1 = x@W1^T.
// Block NB+157: conv/fc weight fold.
__global__ __launch_bounds__(256) void fused_hist_gemm(const int* __restrict__ ei,
        const float* __restrict__ ew,
        const float* __restrict__ x, const float* __restrict__ W1,
        int* __restrict__ hist, float* __restrict__ dhist, int* __restrict__ pcs,
        float* __restrict__ out,
        const float* __restrict__ conv_w, const float* __restrict__ conv_b,
        const float* __restrict__ fc_w, const float* __restrict__ fc_b,
        float* __restrict__ vbuf, float* __restrict__ c0) {
    __shared__ __align__(16) char smem[NPAD * 8];    // 80 KB union
    int t = threadIdx.x;
    int bid = blockIdx.x;
    if (bid < NB) {
        // ---- dual histogram path ----
        int* h = (int*)smem;                         // 40 KB counts
        float* hf = (float*)(smem + NPAD * 4);       // 40 KB weighted degree
        for (int i = t; i < 2 * NPAD; i += 256) ((int*)smem)[i] = 0;
        __syncthreads();
        int e0 = bid * EPB;
        for (int i = t; i < EPB; i += 256) {
            int e = e0 + i;
            int c = ei[N_EDGES + e];
            atomicAdd(&h[c], 1);                     // LDS atomics
            atomicAdd(&hf[c], ew[e]);
        }
        __syncthreads();
        for (int i = t; i < N_NODES; i += 256) {
            hist[bid * N_NODES + i] = h[i];
            dhist[bid * N_NODES + i] = hf[i];
        }
        // chunk count partials: wave w handles chunks w, w+4, ...
        int lane = t & 63, wave = t >> 6;
        for (int cch = wave; cch < NCHUNK; cch += 4) {
            int s = h[cch * 256 + lane] + h[cch * 256 + lane + 64]
                  + h[cch * 256 + lane + 128] + h[cch * 256 + lane + 192];
            #pragma unroll
            for (int off = 32; off > 0; off >>= 1) s += __shfl_down(s, off, 64);
            if (lane == 0) pcs[cch * NB + bid] = s;  // chunk-major layout
        }
        return;
    }
    if (bid == NB + (N_NODES + 63) / 64) {
        // ---- conv/fc weight folding ----
        for (int i = t; i <= 384; i += 256) {
            if (i < 384) {
                float s = 0.0f;
                for (int o = 0; o < CH; ++o) s += fc_w[o] * conv_w[o * 384 + i];
                vbuf[i] = s;
            } else {
                float s = fc_b[0];
                for (int o = 0; o < CH; ++o) s += fc_w[o] * conv_b[o];
                *c0 = s;
            }
        }
        return;
    }
    // ---- gemm path: out[m][o] = sum_k x[m][k] * W1[o][k] ----
    float (*As)[68]  = (float(*)[68])smem;
    float (*Ws)[132] = (float(*)[132])(smem + 32 * 68 * sizeof(float));
    int tx = t & 31;
    int ty = t >> 5;
    int row0 = (bid - NB) * 64;
    float acc[8][4] = {};
    for (int k0 = 0; k0 < 128; k0 += 32) {
        #pragma unroll
        for (int i = 0; i < 8; ++i) {
            int idx = t + i * 256;
            int r = idx >> 5, k = idx & 31;
            int gr = row0 + r;
            As[k][r] = (gr < N_NODES) ? x[gr * CH + k0 + k] : 0.0f;
        }
        #pragma unroll
        for (int i = 0; i < 16; ++i) {
            int idx = t + i * 256;
            int o = idx >> 5, k = idx & 31;
            Ws[k][o] = W1[o * CH + k0 + k];
        }
        __syncthreads();
        #pragma unroll
        for (int kk = 0; kk < 32; ++kk) {
            float a[8], w[4];
            #pragma unroll
            for (int j = 0; j < 8; ++j) a[j] = As[kk][ty * 8 + j];
            #pragma unroll
            for (int c = 0; c < 4; ++c) w[c] = Ws[kk][tx * 4 + c];
            #pragma unroll
            for (int j = 0; j < 8; ++j)
                #pragma unroll
                for (int c = 0; c < 4; ++c)
                    acc[j][c] += a[j] * w[c];
        }
        __syncthreads();
    }
    #pragma unroll
    for (int j = 0; j < 8; ++j) {
        int gr = row0 + ty * 8 + j;
        if (gr < N_NODES) {
            float4 v = make_float4(acc[j][0], acc[j][1], acc[j][2], acc[j][3]);
            *reinterpret_cast<float4*>(&out[gr * CH + tx * 4]) = v;
        }
    }
}

// ---------------------------------------------------------------------------
// K2: per-node totals + dinv + global exclusive prefix + cursor conversion.
__global__ __launch_bounds__(256) void bofs_kernel(int* __restrict__ hist,
        const float* __restrict__ dhist, const int* __restrict__ pcs,
        int* __restrict__ tot, int* __restrict__ offs, float* __restrict__ dinv) {
    __shared__ int wred[4];
    __shared__ int wsum[4];
    __shared__ int base_sh;
    int blk = blockIdx.x, t = threadIdx.x;
    int lane = t & 63, wave = t >> 6;
    // --- base = edges into nodes of earlier chunks ---
    int bsum = 0;
    for (int i = t; i < blk * NB; i += 256) bsum += pcs[i];
    #pragma unroll
    for (int off = 32; off > 0; off >>= 1) bsum += __shfl_down(bsum, off, 64);
    if (lane == 0) wred[wave] = bsum;
    __syncthreads();
    if (t == 0) base_sh = wred[0] + wred[1] + wred[2] + wred[3];
    // --- per-node totals (count + weighted degree) over 64 hist rows ---
    int n = blk * 256 + t;
    int v = 0;
    if (n < N_NODES) {
        float dsum = 0.0f;
        #pragma unroll 8
        for (int b = 0; b < NB; ++b) {
            v += hist[b * N_NODES + n];
            dsum += dhist[b * N_NODES + n];
        }
        tot[n] = v;
        dinv[n] = rsqrtf(dsum + 1.0f);            // +1 = self-loop weight
    }
    // --- 256-wide scan (wave scan + wave offsets) ---
    int s = v;
    #pragma unroll
    for (int off = 1; off < 64; off <<= 1) {
        int u = __shfl_up(s, off, 64);
        if (lane >= off) s += u;
    }
    if (lane == 63) wsum[wave] = s;
    __syncthreads();
    int wbase = 0;
    for (int i = 0; i < wave; ++i) wbase += wsum[i];
    if (n < N_NODES) {
        int run = base_sh + wbase + s - v;        // global exclusive prefix
        offs[n] = run;
        for (int b = 0; b < NB; ++b) {
            int h = hist[b * N_NODES + n];
            hist[b * N_NODES + n] = run;          // column -> start cursor
            run += h;
        }
    }
}

// ---------------------------------------------------------------------------
// K3: scatter edges into CSR order via LDS cursors; records carry the fully
// NORMALIZED value dinv[r]*w*dinv[c] (dinv staged in LDS).
__global__ __launch_bounds__(256) void scatter_kernel(const int* __restrict__ ei,
        const float* __restrict__ ew, const float* __restrict__ dinv,
        const int* __restrict__ bofs, int2* __restrict__ erec) {
    __shared__ int cur[N_NODES];                 // 40 KB
    __shared__ float di[N_NODES];                // 40 KB
    int b = blockIdx.x, t = threadIdx.x;
    for (int i = t; i < N_NODES; i += 256) {
        cur[i] = bofs[b * N_NODES + i];
        di[i] = dinv[i];
    }
    __syncthreads();
    int e0 = b * EPB;
    for (int i = t; i < EPB; i += 256) {
        int e = e0 + i;
        int r = ei[e];
        int c = ei[N_EDGES + e];
        float v = di[r] * ew[e] * di[c];
        int p = atomicAdd(&cur[c], 1);           // LDS atomic
        erec[p] = make_int2(r, __float_as_int(v));
    }
}

// ---------------------------------------------------------------------------
// K4: FUSED agg1 + gemm2. 128 threads / 4 nodes per block (grid 2500 -> ~20
// waves/CU). sched_barrier(0) fences force all 8 gathers in flight before
// any FMA (defeats the compiler's load/use interleaving that kept VGPR=40).
__global__ __launch_bounds__(128, 4) void agg_gemm_kernel(const float4* __restrict__ xw4,
        const int2* __restrict__ erec, const int* __restrict__ offs,
        const int* __restrict__ cnt, const float* __restrict__ dinv,
        const float4* __restrict__ bias4, const float* __restrict__ W2,
        float* __restrict__ out) {
    __shared__ float hs[4][128];                 // 2 KB relu'd h1 rows
    int l = threadIdx.x & 31;                    // channel quad
    int g = threadIdx.x >> 5;                    // node group 0..3
    int n = blockIdx.x * 4 + g;
    float d = dinv[n];
    float dd = d * d;
    float4 self = xw4[n * 32 + l];
    float4 acc = make_float4(dd * self.x, dd * self.y, dd * self.z, dd * self.w);
    int start = offs[n];
    int num = cnt[n];
    int i = 0;
    for (; i + 8 <= num; i += 8) {
        int2 r[8];
        #pragma unroll
        for (int j = 0; j < 8; ++j) r[j] = erec[start + i + j];
        __builtin_amdgcn_sched_barrier(0);       // records issued as a group
        float4 f[8];
        #pragma unroll
        for (int j = 0; j < 8; ++j) f[j] = xw4[r[j].x * 32 + l];
        __builtin_amdgcn_sched_barrier(0);       // 8 gathers in flight
        #pragma unroll
        for (int j = 0; j < 8; ++j) {
            float v = __int_as_float(r[j].y);
            acc.x += v * f[j].x; acc.y += v * f[j].y;
            acc.z += v * f[j].z; acc.w += v * f[j].w;
        }
    }
    for (; i < num; ++i) {
        int2 r = erec[start + i];
        float4 f = xw4[r.x * 32 + l];
        float v = __int_as_float(r.y);
        acc.x += v * f.x; acc.y += v * f.y; acc.z += v * f.z; acc.w += v * f.w;
    }
    float4 bb = bias4[l];
    acc.x = fmaxf(acc.x + bb.x, 0.0f);
    acc.y = fmaxf(acc.y + bb.y, 0.0f);
    acc.z = fmaxf(acc.z + bb.z, 0.0f);
    acc.w = fmaxf(acc.w + bb.w, 0.0f);
    *reinterpret_cast<float4*>(&hs[g][4 * l]) = acc;
    __syncthreads();
    // ---- mini-GEMM: thread = output channel o, all 4 rows ----
    int o = threadIdx.x;
    const float4* w4p = reinterpret_cast<const float4*>(&W2[o * CH]);
    const float4* h0p = reinterpret_cast<const float4*>(&hs[0][0]);
    const float4* h1p = reinterpret_cast<const float4*>(&hs[1][0]);
    const float4* h2p = reinterpret_cast<const float4*>(&hs[2][0]);
    const float4* h3p = reinterpret_cast<const float4*>(&hs[3][0]);
    float a0 = 0.0f, a1 = 0.0f, a2 = 0.0f, a3 = 0.0f;
    #pragma unroll 8
    for (int k4 = 0; k4 < 32; ++k4) {
        float4 w = w4p[k4];                      // L2-hot W2 row
        float4 h0 = h0p[k4], h1 = h1p[k4], h2 = h2p[k4], h3 = h3p[k4];
        a0 += w.x * h0.x + w.y * h0.y + w.z * h0.z + w.w * h0.w;
        a1 += w.x * h1.x + w.y * h1.y + w.z * h1.z + w.w * h1.w;
        a2 += w.x * h2.x + w.y * h2.y + w.z * h2.z + w.w * h2.w;
        a3 += w.x * h3.x + w.y * h3.y + w.z * h3.z + w.w * h3.w;
    }
    int nb = blockIdx.x * 4;
    out[(nb + 0) * CH + o] = a0;
    out[(nb + 1) * CH + o] = a1;
    out[(nb + 2) * CH + o] = a2;
    out[(nb + 3) * CH + o] = a3;
}

// ---------------------------------------------------------------------------
// K5: aggregation layer 2, same 128-thread/4-node + sched_barrier structure.
__global__ __launch_bounds__(128, 4) void agg_kernel(const float4* __restrict__ xw4,
        const int2* __restrict__ erec, const int* __restrict__ offs,
        const int* __restrict__ cnt, const float* __restrict__ dinv,
        const float4* __restrict__ bias4, float4* __restrict__ out4) {
    int l = threadIdx.x & 31;
    int g = threadIdx.x >> 5;
    int n = blockIdx.x * 4 + g;
    float d = dinv[n];
    float dd = d * d;
    float4 self = xw4[n * 32 + l];
    float4 acc = make_float4(dd * self.x, dd * self.y, dd * self.z, dd * self.w);
    int start = offs[n];
    int num = cnt[n];
    int i = 0;
    for (; i + 8 <= num; i += 8) {
        int2 r[8];
        #pragma unroll
        for (int j = 0; j < 8; ++j) r[j] = erec[start + i + j];
        __builtin_amdgcn_sched_barrier(0);
        float4 f[8];
        #pragma unroll
        for (int j = 0; j < 8; ++j) f[j] = xw4[r[j].x * 32 + l];
        __builtin_amdgcn_sched_barrier(0);
        #pragma unroll
        for (int j = 0; j < 8; ++j) {
            float v = __int_as_float(r[j].y);
            acc.x += v * f[j].x; acc.y += v * f[j].y;
            acc.z += v * f[j].z; acc.w += v * f[j].w;
        }
    }
    for (; i < num; ++i) {
        int2 r = erec[start + i];
        float4 f = xw4[r.x * 32 + l];
        float v = __int_as_float(r.y);
        acc.x += v * f.x; acc.y += v * f.y; acc.z += v * f.z; acc.w += v * f.w;
    }
    float4 bb = bias4[l];
    acc.x = fmaxf(acc.x + bb.x, 0.0f);
    acc.y = fmaxf(acc.y + bb.y, 0.0f);
    acc.z = fmaxf(acc.z + bb.z, 0.0f);
    acc.w = fmaxf(acc.w + bb.w, 0.0f);
    out4[n * 32 + l] = acc;
}

// ---------------------------------------------------------------------------
// K6: fused temporal conv + fc: one wave per node, lane handles ch l and l+64.
__global__ __launch_bounds__(256) void convfc_kernel(const float* __restrict__ h,
        const float* __restrict__ v, const float* __restrict__ c0,
        float* __restrict__ out, int N) {
    int n = blockIdx.x * 4 + (threadIdx.x >> 6);
    int l = threadIdx.x & 63;
    if (n >= N) return;
    const float* hn = h + n * CH;
    float v0a = v[l * 3 + 0],        v1a = v[l * 3 + 1],        v2a = v[l * 3 + 2];
    float v0b = v[(l + 64) * 3 + 0], v1b = v[(l + 64) * 3 + 1], v2b = v[(l + 64) * 3 + 2];
    float p = hn[l] * v1a + hn[l + 64] * v1b;
    if (n > 0)     p += hn[l - CH] * v0a + hn[l + 64 - CH] * v0b;
    if (n < N - 1) p += hn[l + CH] * v2a + hn[l + 64 + CH] * v2b;
    #pragma unroll
    for (int off = 32; off > 0; off >>= 1) p += __shfl_down(p, off, 64);
    if (l == 0) out[n] = p + *c0;
}

// ---------------------------------------------------------------------------
extern "C" void kernel_launch(void* const* d_in, const int* in_sizes, int n_in,
                              void* d_out, int out_size, void* d_ws, size_t ws_size,
                              hipStream_t stream) {
    const float* x       = (const float*)d_in[0];
    const int*   ei      = (const int*)d_in[1];
    const float* ew      = (const float*)d_in[2];
    const float* W1      = (const float*)d_in[3];
    const float* b1      = (const float*)d_in[4];
    const float* W2      = (const float*)d_in[5];
    const float* b2      = (const float*)d_in[6];
    const float* conv_w  = (const float*)d_in[7];
    const float* conv_b  = (const float*)d_in[8];
    const float* fc_w    = (const float*)d_in[9];
    const float* fc_b    = (const float*)d_in[10];
    float* out = (float*)d_out;

    float* bufA   = (float*)d_ws;                   // 1,280,000 f (xw1, later h2)
    float* bufB   = bufA + N_NODES * CH;            // 1,280,000 f (xw2)
    int2*  erec   = (int2*)(bufB + N_NODES * CH);   // 640,000 x 8B
    int*   hist   = (int*)(erec + N_EDGES);         // NB*10,000 i
    float* dhist  = (float*)(hist + NB * N_NODES);  // NB*10,000 f
    int*   pcs    = (int*)(dhist + NB * N_NODES);   // NCHUNK*NB i
    int*   tot    = pcs + NCHUNK * NB;              // 10,000 i
    int*   offs   = tot + N_NODES;                  // 10,000 i
    float* dinv   = (float*)(offs + N_NODES);       // 10,000 f
    float* vbuf   = dinv + N_NODES;                 // 384 f
    float* c0     = vbuf + 384;                     // 1 f

    const int gemm_grid = (N_NODES + 63) / 64;      // 157

    // K1: dual-hist (64) + gemm1 (157) + weight-fold (1), all data-independent
    fused_hist_gemm<<<NB + gemm_grid + 1, 256, 0, stream>>>(ei, ew, x, W1,
            hist, dhist, pcs, bufA, conv_w, conv_b, fc_w, fc_b, vbuf, c0);
    // K2: totals + dinv + prefix + cursor conversion
    bofs_kernel<<<NCHUNK, 256, 0, stream>>>(hist, dhist, pcs, tot, offs, dinv);
    // K3: normalized CSR scatter
    scatter_kernel<<<NB, 256, 0, stream>>>(ei, ew, dinv, hist, erec);
    // K4: agg1 + gemm2 fused (4 nodes/block, forced 8-deep MLP): bufA -> bufB
    agg_gemm_kernel<<<N_NODES / 4, 128, 0, stream>>>((const float4*)bufA, erec, offs,
            tot, dinv, (const float4*)b1, W2, bufB);
    // K5: agg layer 2 (4 nodes/block, forced 8-deep MLP): bufB -> bufA
    agg_kernel<<<N_NODES / 4, 128, 0, stream>>>((const float4*)bufB, erec, offs, tot,
                                                dinv, (const float4*)b2, (float4*)bufA);
    // K6: fused temporal conv + fc
    convfc_kernel<<<(N_NODES + 3) / 4, 256, 0, stream>>>(bufA, vbuf, c0, out, N_NODES);
}

// Round 7
// 211.379 us; speedup vs baseline: 1.0677x; 1.0060x over previous
//
#include <hip/hip_runtime.h>
#include <hip/hip_bf16.h>

#define N_NODES 10000
#define N_EDGES 640000
#define CH 128
#define NB 64                // histogram/scatter blocks
#define EPB (N_EDGES / NB)   // 10000 edges per block
#define NCHUNK 40            // ceil(N_NODES/256) scan chunks
#define NPAD 10240           // NCHUNK*256

// ---------------------------------------------------------------------------
// K1: FUSED. Blocks [0,NB): per-block LDS DUAL histogram (count + weighted
// degree, 80 KB) + chunk count-partials. Blocks [NB, NB+157): gemm1 = x@W1^T.
// Block NB+157: conv/fc weight fold.
__global__ __launch_bounds__(256) void fused_hist_gemm(const int* __restrict__ ei,
        const float* __restrict__ ew,
        const float* __restrict__ x, const float* __restrict__ W1,
        int* __restrict__ hist, float* __restrict__ dhist, int* __restrict__ pcs,
        float* __restrict__ out,
        const float* __restrict__ conv_w, const float* __restrict__ conv_b,
        const float* __restrict__ fc_w, const float* __restrict__ fc_b,
        float* __restrict__ vbuf, float* __restrict__ c0) {
    __shared__ __align__(16) char smem[NPAD * 8];    // 80 KB union
    int t = threadIdx.x;
    int bid = blockIdx.x;
    if (bid < NB) {
        // ---- dual histogram path ----
        int* h = (int*)smem;                         // 40 KB counts
        float* hf = (float*)(smem + NPAD * 4);       // 40 KB weighted degree
        for (int i = t; i < 2 * NPAD; i += 256) ((int*)smem)[i] = 0;
        __syncthreads();
        int e0 = bid * EPB;
        for (int i = t; i < EPB; i += 256) {
            int e = e0 + i;
            int c = ei[N_EDGES + e];
            atomicAdd(&h[c], 1);                     // LDS atomics
            atomicAdd(&hf[c], ew[e]);
        }
        __syncthreads();
        for (int i = t; i < N_NODES; i += 256) {
            hist[bid * N_NODES + i] = h[i];
            dhist[bid * N_NODES + i] = hf[i];
        }
        // chunk count partials: wave w handles chunks w, w+4, ...
        int lane = t & 63, wave = t >> 6;
        for (int cch = wave; cch < NCHUNK; cch += 4) {
            int s = h[cch * 256 + lane] + h[cch * 256 + lane + 64]
                  + h[cch * 256 + lane + 128] + h[cch * 256 + lane + 192];
            #pragma unroll
            for (int off = 32; off > 0; off >>= 1) s += __shfl_down(s, off, 64);
            if (lane == 0) pcs[cch * NB + bid] = s;  // chunk-major layout
        }
        return;
    }
    if (bid == NB + (N_NODES + 63) / 64) {
        // ---- conv/fc weight folding ----
        for (int i = t; i <= 384; i += 256) {
            if (i < 384) {
                float s = 0.0f;
                for (int o = 0; o < CH; ++o) s += fc_w[o] * conv_w[o * 384 + i];
                vbuf[i] = s;
            } else {
                float s = fc_b[0];
                for (int o = 0; o < CH; ++o) s += fc_w[o] * conv_b[o];
                *c0 = s;
            }
        }
        return;
    }
    // ---- gemm path: out[m][o] = sum_k x[m][k] * W1[o][k] ----
    float (*As)[68]  = (float(*)[68])smem;
    float (*Ws)[132] = (float(*)[132])(smem + 32 * 68 * sizeof(float));
    int tx = t & 31;
    int ty = t >> 5;
    int row0 = (bid - NB) * 64;
    float acc[8][4] = {};
    for (int k0 = 0; k0 < 128; k0 += 32) {
        #pragma unroll
        for (int i = 0; i < 8; ++i) {
            int idx = t + i * 256;
            int r = idx >> 5, k = idx & 31;
            int gr = row0 + r;
            As[k][r] = (gr < N_NODES) ? x[gr * CH + k0 + k] : 0.0f;
        }
        #pragma unroll
        for (int i = 0; i < 16; ++i) {
            int idx = t + i * 256;
            int o = idx >> 5, k = idx & 31;
            Ws[k][o] = W1[o * CH + k0 + k];
        }
        __syncthreads();
        #pragma unroll
        for (int kk = 0; kk < 32; ++kk) {
            float a[8], w[4];
            #pragma unroll
            for (int j = 0; j < 8; ++j) a[j] = As[kk][ty * 8 + j];
            #pragma unroll
            for (int c = 0; c < 4; ++c) w[c] = Ws[kk][tx * 4 + c];
            #pragma unroll
            for (int j = 0; j < 8; ++j)
                #pragma unroll
                for (int c = 0; c < 4; ++c)
                    acc[j][c] += a[j] * w[c];
        }
        __syncthreads();
    }
    #pragma unroll
    for (int j = 0; j < 8; ++j) {
        int gr = row0 + ty * 8 + j;
        if (gr < N_NODES) {
            float4 v = make_float4(acc[j][0], acc[j][1], acc[j][2], acc[j][3]);
            *reinterpret_cast<float4*>(&out[gr * CH + tx * 4]) = v;
        }
    }
}

// ---------------------------------------------------------------------------
// K2: per-node totals + dinv + global exclusive prefix + cursor conversion.
__global__ __launch_bounds__(256) void bofs_kernel(int* __restrict__ hist,
        const float* __restrict__ dhist, const int* __restrict__ pcs,
        int* __restrict__ tot, int* __restrict__ offs, float* __restrict__ dinv) {
    __shared__ int wred[4];
    __shared__ int wsum[4];
    __shared__ int base_sh;
    int blk = blockIdx.x, t = threadIdx.x;
    int lane = t & 63, wave = t >> 6;
    // --- base = edges into nodes of earlier chunks ---
    int bsum = 0;
    for (int i = t; i < blk * NB; i += 256) bsum += pcs[i];
    #pragma unroll
    for (int off = 32; off > 0; off >>= 1) bsum += __shfl_down(bsum, off, 64);
    if (lane == 0) wred[wave] = bsum;
    __syncthreads();
    if (t == 0) base_sh = wred[0] + wred[1] + wred[2] + wred[3];
    // --- per-node totals (count + weighted degree) over 64 hist rows ---
    int n = blk * 256 + t;
    int v = 0;
    if (n < N_NODES) {
        float dsum = 0.0f;
        #pragma unroll 8
        for (int b = 0; b < NB; ++b) {
            v += hist[b * N_NODES + n];
            dsum += dhist[b * N_NODES + n];
        }
        tot[n] = v;
        dinv[n] = rsqrtf(dsum + 1.0f);            // +1 = self-loop weight
    }
    // --- 256-wide scan (wave scan + wave offsets) ---
    int s = v;
    #pragma unroll
    for (int off = 1; off < 64; off <<= 1) {
        int u = __shfl_up(s, off, 64);
        if (lane >= off) s += u;
    }
    if (lane == 63) wsum[wave] = s;
    __syncthreads();
    int wbase = 0;
    for (int i = 0; i < wave; ++i) wbase += wsum[i];
    if (n < N_NODES) {
        int run = base_sh + wbase + s - v;        // global exclusive prefix
        offs[n] = run;
        for (int b = 0; b < NB; ++b) {
            int h = hist[b * N_NODES + n];
            hist[b * N_NODES + n] = run;          // column -> start cursor
            run += h;
        }
    }
}

// ---------------------------------------------------------------------------
// K3: scatter edges into CSR order via LDS cursors; records carry the fully
// NORMALIZED value dinv[r]*w*dinv[c] (dinv staged in LDS).
__global__ __launch_bounds__(256) void scatter_kernel(const int* __restrict__ ei,
        const float* __restrict__ ew, const float* __restrict__ dinv,
        const int* __restrict__ bofs, int2* __restrict__ erec) {
    __shared__ int cur[N_NODES];                 // 40 KB
    __shared__ float di[N_NODES];                // 40 KB
    int b = blockIdx.x, t = threadIdx.x;
    for (int i = t; i < N_NODES; i += 256) {
        cur[i] = bofs[b * N_NODES + i];
        di[i] = dinv[i];
    }
    __syncthreads();
    int e0 = b * EPB;
    for (int i = t; i < EPB; i += 256) {
        int e = e0 + i;
        int r = ei[e];
        int c = ei[N_EDGES + e];
        float v = di[r] * ew[e] * di[c];
        int p = atomicAdd(&cur[c], 1);           // LDS atomic
        erec[p] = make_int2(r, __float_as_int(v));
    }
}

// ---------------------------------------------------------------------------
// K3b: regroup each CSR segment by SOURCE TILE (src>>11, 5 tiles of 2048).
// All agg blocks then sweep src tiles in the same order -> instantaneous
// gather working set ~1 MB -> L2-resident on every XCD (beats L3 thrash).
// Permutation within a segment: offs/cnt unchanged.
__global__ __launch_bounds__(256) void regroup_kernel(const int2* __restrict__ erec,
        const int* __restrict__ offs, const int* __restrict__ cnt,
        int2* __restrict__ erec2) {
    __shared__ int curs[8][5];                   // per-(node, tile) cursor
    int g = threadIdx.x >> 5;                    // node group 0..7
    int l = threadIdx.x & 31;
    int n = blockIdx.x * 8 + g;
    int start = offs[n];
    int num = cnt[n];
    // count per tile
    int c0 = 0, c1 = 0, c2 = 0, c3 = 0;
    for (int i = l; i < num; i += 32) {
        int tl = erec[start + i].x >> 11;
        c0 += (tl == 0); c1 += (tl == 1); c2 += (tl == 2); c3 += (tl == 3);
    }
    #pragma unroll
    for (int off = 16; off > 0; off >>= 1) {
        c0 += __shfl_down(c0, off, 32);
        c1 += __shfl_down(c1, off, 32);
        c2 += __shfl_down(c2, off, 32);
        c3 += __shfl_down(c3, off, 32);
    }
    if (l == 0) {
        curs[g][0] = start;
        curs[g][1] = start + c0;
        curs[g][2] = start + c0 + c1;
        curs[g][3] = start + c0 + c1 + c2;
        curs[g][4] = start + c0 + c1 + c2 + c3;
    }
    __syncthreads();
    // scatter into tile-grouped order (intra-tile order arbitrary)
    for (int i = l; i < num; i += 32) {
        int2 rec = erec[start + i];              // L2-hot (just written)
        int tl = rec.x >> 11;
        int p = atomicAdd(&curs[g][tl], 1);      // LDS atomic
        erec2[p] = rec;
    }
}

// ---------------------------------------------------------------------------
// K4: FUSED agg1 + gemm2 (round-4 proven shape: 256 thr, 8 nodes, 8-deep).
__global__ __launch_bounds__(256) void agg_gemm_kernel(const float4* __restrict__ xw4,
        const int2* __restrict__ erec, const int* __restrict__ offs,
        const int* __restrict__ cnt, const float* __restrict__ dinv,
        const float4* __restrict__ bias4, const float* __restrict__ W2,
        float* __restrict__ out) {
    __shared__ float hs[8][128];                 // 4 KB relu'd h1 rows
    int l = threadIdx.x & 31;                    // channel quad
    int g = threadIdx.x >> 5;                    // node group 0..7
    int n = blockIdx.x * 8 + g;
    float d = dinv[n];
    float dd = d * d;
    float4 self = xw4[n * 32 + l];
    float4 acc = make_float4(dd * self.x, dd * self.y, dd * self.z, dd * self.w);
    int start = offs[n];
    int num = cnt[n];
    int i = 0;
    for (; i + 8 <= num; i += 8) {
        int2 r[8];
        #pragma unroll
        for (int j = 0; j < 8; ++j) r[j] = erec[start + i + j];
        float4 f[8];
        #pragma unroll
        for (int j = 0; j < 8; ++j) f[j] = xw4[r[j].x * 32 + l];
        #pragma unroll
        for (int j = 0; j < 8; ++j) {
            float v = __int_as_float(r[j].y);
            acc.x += v * f[j].x; acc.y += v * f[j].y;
            acc.z += v * f[j].z; acc.w += v * f[j].w;
        }
    }
    for (; i < num; ++i) {
        int2 r = erec[start + i];
        float4 f = xw4[r.x * 32 + l];
        float v = __int_as_float(r.y);
        acc.x += v * f.x; acc.y += v * f.y; acc.z += v * f.z; acc.w += v * f.w;
    }
    float4 bb = bias4[l];
    acc.x = fmaxf(acc.x + bb.x, 0.0f);
    acc.y = fmaxf(acc.y + bb.y, 0.0f);
    acc.z = fmaxf(acc.z + bb.z, 0.0f);
    acc.w = fmaxf(acc.w + bb.w, 0.0f);
    *reinterpret_cast<float4*>(&hs[g][4 * l]) = acc;
    __syncthreads();
    // ---- mini-GEMM: thread = (output channel o, row-group rg of 4 rows) ----
    int o = threadIdx.x & 127;
    int rg = threadIdx.x >> 7;                   // 0: rows 0-3, 1: rows 4-7
    const float4* w4p = reinterpret_cast<const float4*>(&W2[o * CH]);
    const float4* h0p = reinterpret_cast<const float4*>(&hs[rg * 4 + 0][0]);
    const float4* h1p = reinterpret_cast<const float4*>(&hs[rg * 4 + 1][0]);
    const float4* h2p = reinterpret_cast<const float4*>(&hs[rg * 4 + 2][0]);
    const float4* h3p = reinterpret_cast<const float4*>(&hs[rg * 4 + 3][0]);
    float a0 = 0.0f, a1 = 0.0f, a2 = 0.0f, a3 = 0.0f;
    #pragma unroll 8
    for (int k4 = 0; k4 < 32; ++k4) {
        float4 w = w4p[k4];                      // L2-hot W2 row
        float4 h0 = h0p[k4], h1 = h1p[k4], h2 = h2p[k4], h3 = h3p[k4];
        a0 += w.x * h0.x + w.y * h0.y + w.z * h0.z + w.w * h0.w;
        a1 += w.x * h1.x + w.y * h1.y + w.z * h1.z + w.w * h1.w;
        a2 += w.x * h2.x + w.y * h2.y + w.z * h2.z + w.w * h2.w;
        a3 += w.x * h3.x + w.y * h3.y + w.z * h3.z + w.w * h3.w;
    }
    int nb = blockIdx.x * 8 + rg * 4;
    out[(nb + 0) * CH + o] = a0;
    out[(nb + 1) * CH + o] = a1;
    out[(nb + 2) * CH + o] = a2;
    out[(nb + 3) * CH + o] = a3;
}

// ---------------------------------------------------------------------------
// K5: aggregation layer 2 (round-4 proven shape).
__global__ __launch_bounds__(256) void agg_kernel(const float4* __restrict__ xw4,
        const int2* __restrict__ erec, const int* __restrict__ offs,
        const int* __restrict__ cnt, const float* __restrict__ dinv,
        const float4* __restrict__ bias4, float4* __restrict__ out4) {
    int l = threadIdx.x & 31;
    int g = threadIdx.x >> 5;
    int n = blockIdx.x * 8 + g;
    float d = dinv[n];
    float dd = d * d;
    float4 self = xw4[n * 32 + l];
    float4 acc = make_float4(dd * self.x, dd * self.y, dd * self.z, dd * self.w);
    int start = offs[n];
    int num = cnt[n];
    int i = 0;
    for (; i + 8 <= num; i += 8) {
        int2 r[8];
        #pragma unroll
        for (int j = 0; j < 8; ++j) r[j] = erec[start + i + j];
        float4 f[8];
        #pragma unroll
        for (int j = 0; j < 8; ++j) f[j] = xw4[r[j].x * 32 + l];
        #pragma unroll
        for (int j = 0; j < 8; ++j) {
            float v = __int_as_float(r[j].y);
            acc.x += v * f[j].x; acc.y += v * f[j].y;
            acc.z += v * f[j].z; acc.w += v * f[j].w;
        }
    }
    for (; i < num; ++i) {
        int2 r = erec[start + i];
        float4 f = xw4[r.x * 32 + l];
        float v = __int_as_float(r.y);
        acc.x += v * f.x; acc.y += v * f.y; acc.z += v * f.z; acc.w += v * f.w;
    }
    float4 bb = bias4[l];
    acc.x = fmaxf(acc.x + bb.x, 0.0f);
    acc.y = fmaxf(acc.y + bb.y, 0.0f);
    acc.z = fmaxf(acc.z + bb.z, 0.0f);
    acc.w = fmaxf(acc.w + bb.w, 0.0f);
    out4[n * 32 + l] = acc;
}

// ---------------------------------------------------------------------------
// K6: fused temporal conv + fc: one wave per node, lane handles ch l and l+64.
__global__ __launch_bounds__(256) void convfc_kernel(const float* __restrict__ h,
        const float* __restrict__ v, const float* __restrict__ c0,
        float* __restrict__ out, int N) {
    int n = blockIdx.x * 4 + (threadIdx.x >> 6);
    int l = threadIdx.x & 63;
    if (n >= N) return;
    const float* hn = h + n * CH;
    float v0a = v[l * 3 + 0],        v1a = v[l * 3 + 1],        v2a = v[l * 3 + 2];
    float v0b = v[(l + 64) * 3 + 0], v1b = v[(l + 64) * 3 + 1], v2b = v[(l + 64) * 3 + 2];
    float p = hn[l] * v1a + hn[l + 64] * v1b;
    if (n > 0)     p += hn[l - CH] * v0a + hn[l + 64 - CH] * v0b;
    if (n < N - 1) p += hn[l + CH] * v2a + hn[l + 64 + CH] * v2b;
    #pragma unroll
    for (int off = 32; off > 0; off >>= 1) p += __shfl_down(p, off, 64);
    if (l == 0) out[n] = p + *c0;
}

// ---------------------------------------------------------------------------
extern "C" void kernel_launch(void* const* d_in, const int* in_sizes, int n_in,
                              void* d_out, int out_size, void* d_ws, size_t ws_size,
                              hipStream_t stream) {
    const float* x       = (const float*)d_in[0];
    const int*   ei      = (const int*)d_in[1];
    const float* ew      = (const float*)d_in[2];
    const float* W1      = (const float*)d_in[3];
    const float* b1      = (const float*)d_in[4];
    const float* W2      = (const float*)d_in[5];
    const float* b2      = (const float*)d_in[6];
    const float* conv_w  = (const float*)d_in[7];
    const float* conv_b  = (const float*)d_in[8];
    const float* fc_w    = (const float*)d_in[9];
    const float* fc_b    = (const float*)d_in[10];
    float* out = (float*)d_out;

    float* bufA   = (float*)d_ws;                   // 1,280,000 f (xw1, later h2)
    float* bufB   = bufA + N_NODES * CH;            // 1,280,000 f (xw2)
    int2*  erec   = (int2*)(bufB + N_NODES * CH);   // 640,000 x 8B (scatter order)
    int2*  erec2  = erec + N_EDGES;                 // 640,000 x 8B (tile-grouped)
    int*   hist   = (int*)(erec2 + N_EDGES);        // NB*10,000 i
    float* dhist  = (float*)(hist + NB * N_NODES);  // NB*10,000 f
    int*   pcs    = (int*)(dhist + NB * N_NODES);   // NCHUNK*NB i
    int*   tot    = pcs + NCHUNK * NB;              // 10,000 i
    int*   offs   = tot + N_NODES;                  // 10,000 i
    float* dinv   = (float*)(offs + N_NODES);       // 10,000 f
    float* vbuf   = dinv + N_NODES;                 // 384 f
    float* c0     = vbuf + 384;                     // 1 f

    const int gemm_grid = (N_NODES + 63) / 64;      // 157

    // K1: dual-hist (64) + gemm1 (157) + weight-fold (1), all data-independent
    fused_hist_gemm<<<NB + gemm_grid + 1, 256, 0, stream>>>(ei, ew, x, W1,
            hist, dhist, pcs, bufA, conv_w, conv_b, fc_w, fc_b, vbuf, c0);
    // K2: totals + dinv + prefix + cursor conversion
    bofs_kernel<<<NCHUNK, 256, 0, stream>>>(hist, dhist, pcs, tot, offs, dinv);
    // K3: normalized CSR scatter
    scatter_kernel<<<NB, 256, 0, stream>>>(ei, ew, dinv, hist, erec);
    // K3b: regroup segments by source tile -> erec2 (L2-sweep locality)
    regroup_kernel<<<N_NODES / 8, 256, 0, stream>>>(erec, offs, tot, erec2);
    // K4: agg1 + gemm2 fused: bufA -> bufB
    agg_gemm_kernel<<<N_NODES / 8, 256, 0, stream>>>((const float4*)bufA, erec2, offs,
            tot, dinv, (const float4*)b1, W2, bufB);
    // K5: agg layer 2: bufB -> bufA
    agg_kernel<<<N_NODES / 8, 256, 0, stream>>>((const float4*)bufB, erec2, offs, tot,
                                                dinv, (const float4*)b2, (float4*)bufA);
    // K6: fused temporal conv + fc
    convfc_kernel<<<(N_NODES + 3) / 4, 256, 0, stream>>>(bufA, vbuf, c0, out, N_NODES);
}